// Round 4
// baseline (237.106 us; speedup 1.0000x reference)
//
#include <hip/hip_runtime.h>
#include <math.h>

// LayerNorm_v2: B=8, S=4096, D=1024, f32 in / f32 out.
// Reference quirks replicated:
//  - stats from batch 0 only, broadcast over all batches
//  - "buggy Welford": mean_k=(mean_{k-1}+d_k)/k ; var += (d_k-mean_k)^2 ; var/=(D-1)
//
// v5 (from v4): (a) x loads are REGULAR cached loads (NT loads bypass L2 and
// under-run the 6.29 TB/s copy ceiling; NT kept on stores only, where it
// prevents write-allocate pollution). (b) streaming normalize folded to one
// FMA per element via per-row scale/bias: sc=alpha*r, bs=beta-mf*sc.
// Lane L owns float4 slots L+64c (c=0..3): every load/store is 64x16B
// contiguous. Stats = 4 short recurrence chains per lane seeded by the
// 6-term closed-form factorial-decay series (neighbor elems via shuffles).
#define BB 8
#define SS 4096
#define DD 1024
#define EPSF 1e-5f

typedef float f32x4 __attribute__((ext_vector_type(4)));

__device__ __forceinline__ f32x4 shfl4(const f32x4 v, int lane) {
    f32x4 r;
    r.x = __shfl(v.x, lane, 64);
    r.y = __shfl(v.y, lane, 64);
    r.z = __shfl(v.z, lane, 64);
    r.w = __shfl(v.w, lane, 64);
    return r;
}
__device__ __forceinline__ f32x4 shfl4_up1(const f32x4 v) {
    f32x4 r;
    r.x = __shfl_up(v.x, 1, 64);
    r.y = __shfl_up(v.y, 1, 64);
    r.z = __shfl_up(v.z, 1, 64);
    r.w = __shfl_up(v.w, 1, 64);
    return r;
}

__global__ __launch_bounds__(256) void fused_ln_kernel(
    const float* __restrict__ x,
    const float* __restrict__ alpha,
    const float* __restrict__ beta,
    float* __restrict__ out)
{
    const int L   = threadIdx.x & 63;          // lane
    const int wv  = threadIdx.x >> 6;          // wave in block
    const int row = (blockIdx.x << 2) | wv;    // 0..4095, one row per wave
    const size_t row4   = (size_t)row * (DD / 4);
    const size_t batch4 = (size_t)SS * (DD / 4);

    const f32x4* __restrict__ xp = reinterpret_cast<const f32x4*>(x);
    f32x4*       __restrict__ op = reinterpret_cast<f32x4*>(out);

    // ---- batch-0 row, coalesced: lane L holds slots L+64c (floats 256c+4L..+3)
    f32x4 v[4];
#pragma unroll
    for (int c = 0; c < 4; ++c)
        v[c] = xp[row4 + L + 64 * c];

    // ---- issue batch-1 + alpha/beta loads EARLY (independent of stats ALU)
    size_t cb = batch4 + row4;                 // current batch base (batch 1)
    f32x4 cur[4];
#pragma unroll
    for (int c = 0; c < 4; ++c)
        cur[c] = xp[cb + L + 64 * c];

    const f32x4* __restrict__ a4 = reinterpret_cast<const f32x4*>(alpha);
    const f32x4* __restrict__ b4 = reinterpret_cast<const f32x4*>(beta);
    f32x4 av[4], bv[4];
#pragma unroll
    for (int c = 0; c < 4; ++c) { av[c] = a4[L + 64 * c]; bv[c] = b4[L + 64 * c]; }

    // ---- stats: 4 chains per lane; chain c covers k in [j0+1, j0+4], j0=256c+4L.
    float var    = 0.0f;
    float m_last = 0.0f;
#pragma unroll
    for (int c = 0; c < 4; ++c) {
        const f32x4 up1 = shfl4_up1(v[c]);                 // lane L-1's chunk c
        const float u2z = __shfl_up(v[c].z, 2, 64);        // lane L-2 .z
        const float u2w = __shfl_up(v[c].w, 2, 64);        // lane L-2 .w
        f32x4 wrap1 = {0.f, 0.f, 0.f, 0.f};
        float wz = 0.f, ww = 0.f;
        if (c > 0) {                                       // compile-time (unrolled)
            wrap1 = shfl4(v[c - 1], 63);                   // elements 256c-4..256c-1
            wz = __shfl(v[c - 1].z, 62, 64);               // element 256c-6
            ww = __shfl(v[c - 1].w, 62, 64);               // element 256c-5
        }

        const float jf = (float)(256 * c + 4 * L);         // j0
        float m;
        if (c == 0 && L == 0) {
            m = 0.0f;                                      // mean_0, exact
        } else if (c == 0 && L == 1) {
            // exact: mean_4 = d4/4 + d3/12 + (d2+d1)/24
            m = up1.w * 0.25f + up1.z * (1.0f / 12.0f)
              + (up1.y + up1.x) * (1.0f / 24.0f);
        } else {
            // window w0..w5 = elements j0-6..j0-1
            const f32x4 w25 = (L == 0) ? wrap1 : up1;      // w2..w5
            float w0, w1;
            if (L >= 2)      { w0 = u2z;     w1 = u2w;     }
            else if (L == 1) { w0 = wrap1.z; w1 = wrap1.w; }
            else             { w0 = wz;      w1 = ww;      }
            float acc = w0;
            acc = fmaf(acc, __builtin_amdgcn_rcpf(jf - 5.0f), w1);
            acc = fmaf(acc, __builtin_amdgcn_rcpf(jf - 4.0f), w25.x);
            acc = fmaf(acc, __builtin_amdgcn_rcpf(jf - 3.0f), w25.y);
            acc = fmaf(acc, __builtin_amdgcn_rcpf(jf - 2.0f), w25.z);
            acc = fmaf(acc, __builtin_amdgcn_rcpf(jf - 1.0f), w25.w);
            m = acc * __builtin_amdgcn_rcpf(jf);
        }

        const float dd[4] = { v[c].x, v[c].y, v[c].z, v[c].w };
#pragma unroll
        for (int t = 0; t < 4; ++t) {
            m = (m + dd[t]) * __builtin_amdgcn_rcpf(jf + (float)(t + 1));
            const float df = dd[t] - m;
            var = fmaf(df, df, var);
        }
        m_last = m;                                        // c=3 end = mean_1024
    }

    // Butterfly: every lane gets the full var; broadcast mean_1024 from lane 63.
#pragma unroll
    for (int off = 32; off >= 1; off >>= 1) var += __shfl_xor(var, off, 64);
    const float mf = __shfl(m_last, 63, 64);
    const float r  = rsqrtf(var * (1.0f / 1023.0f) + EPSF);

    // ---- per-row scale/bias: out = x*sc + bs  (1 FMA per element streaming)
    f32x4 sc[4], bs[4];
#pragma unroll
    for (int c = 0; c < 4; ++c) {
        sc[c].x = av[c].x * r;  sc[c].y = av[c].y * r;
        sc[c].z = av[c].z * r;  sc[c].w = av[c].w * r;
        bs[c].x = fmaf(-mf, sc[c].x, bv[c].x);
        bs[c].y = fmaf(-mf, sc[c].y, bv[c].y);
        bs[c].z = fmaf(-mf, sc[c].z, bv[c].z);
        bs[c].w = fmaf(-mf, sc[c].w, bv[c].w);
    }

    // ---- normalize batch 0 straight from registers (coalesced NT stores)
#pragma unroll
    for (int c = 0; c < 4; ++c) {
        f32x4 o;
        o.x = fmaf(v[c].x, sc[c].x, bs[c].x);
        o.y = fmaf(v[c].y, sc[c].y, bs[c].y);
        o.z = fmaf(v[c].z, sc[c].z, bs[c].z);
        o.w = fmaf(v[c].w, sc[c].w, bs[c].w);
        __builtin_nontemporal_store(o, op + row4 + L + 64 * c);
    }

    // ---- stream batches 1..7, depth-2 pipeline (load b+1 before storing b)
#pragma unroll
    for (int b = 1; b <= 6; ++b) {
        f32x4 nxt[4];
#pragma unroll
        for (int c = 0; c < 4; ++c)
            nxt[c] = xp[cb + batch4 + L + 64 * c];
#pragma unroll
        for (int c = 0; c < 4; ++c) {
            f32x4 o;
            o.x = fmaf(cur[c].x, sc[c].x, bs[c].x);
            o.y = fmaf(cur[c].y, sc[c].y, bs[c].y);
            o.z = fmaf(cur[c].z, sc[c].z, bs[c].z);
            o.w = fmaf(cur[c].w, sc[c].w, bs[c].w);
            __builtin_nontemporal_store(o, op + cb + L + 64 * c);
        }
#pragma unroll
        for (int c = 0; c < 4; ++c) cur[c] = nxt[c];
        cb += batch4;
    }
    // epilogue: batch 7
#pragma unroll
    for (int c = 0; c < 4; ++c) {
        f32x4 o;
        o.x = fmaf(cur[c].x, sc[c].x, bs[c].x);
        o.y = fmaf(cur[c].y, sc[c].y, bs[c].y);
        o.z = fmaf(cur[c].z, sc[c].z, bs[c].z);
        o.w = fmaf(cur[c].w, sc[c].w, bs[c].w);
        __builtin_nontemporal_store(o, op + cb + L + 64 * c);
    }
}

extern "C" void kernel_launch(void* const* d_in, const int* in_sizes, int n_in,
                              void* d_out, int out_size, void* d_ws, size_t ws_size,
                              hipStream_t stream) {
    (void)in_sizes; (void)n_in; (void)out_size; (void)d_ws; (void)ws_size;
    const float* x     = (const float*)d_in[0];   // (8, 4096, 1024) f32
    const float* alpha = (const float*)d_in[1];   // (1024,) f32
    const float* beta  = (const float*)d_in[2];   // (1024,) f32
    float* out = (float*)d_out;

    hipLaunchKernelGGL(fused_ln_kernel, dim3(SS / 4), dim3(256), 0, stream,
                       x, alpha, beta, out);
}

// Round 5
// 236.778 us; speedup vs baseline: 1.0014x; 1.0014x over previous
//
#include <hip/hip_runtime.h>
#include <math.h>

// LayerNorm_v2: B=8, S=4096, D=1024, f32 in / f32 out.
// Reference quirks replicated:
//  - stats from batch 0 only, broadcast over all batches
//  - "buggy Welford": mean_k=(mean_{k-1}+d_k)/k ; var += (d_k-mean_k)^2 ; var/=(D-1)
//
// v6: NT loads restored (v5's cached loads thrashed L2 behind the NT store
// stream: FETCH halved but BW dropped 4.7->3.2 TB/s effective). Occupancy
// doubled: 2 waves per row, each redundantly computes stats from its own
// batch-0 load (back-to-back same-line requests MSHR-merge), then half 0
// writes batches 0-3 (batch 0 straight from registers), half 1 writes 4-7.
// Grid 2048x256 = 32 waves/CU; __launch_bounds__(256,8) keeps VGPR<=64 so
// all 8 blocks/CU are resident. Streaming epilogue is 1 FMA/element via
// per-row scale/bias (sc=alpha*r, bs=beta-mf*sc), alpha/beta consumed
// chunk-wise so they are never all live.
#define BB 8
#define SS 4096
#define DD 1024
#define EPSF 1e-5f

typedef float f32x4 __attribute__((ext_vector_type(4)));

__device__ __forceinline__ f32x4 shfl4(const f32x4 v, int lane) {
    f32x4 r;
    r.x = __shfl(v.x, lane, 64);
    r.y = __shfl(v.y, lane, 64);
    r.z = __shfl(v.z, lane, 64);
    r.w = __shfl(v.w, lane, 64);
    return r;
}
__device__ __forceinline__ f32x4 shfl4_up1(const f32x4 v) {
    f32x4 r;
    r.x = __shfl_up(v.x, 1, 64);
    r.y = __shfl_up(v.y, 1, 64);
    r.z = __shfl_up(v.z, 1, 64);
    r.w = __shfl_up(v.w, 1, 64);
    return r;
}

__global__ __launch_bounds__(256, 8) void fused_ln_kernel(
    const float* __restrict__ x,
    const float* __restrict__ alpha,
    const float* __restrict__ beta,
    float* __restrict__ out)
{
    const int L    = threadIdx.x & 63;         // lane
    const int wv   = threadIdx.x >> 6;         // wave 0..3
    const int half = wv & 1;                   // 0: batches 0-3, 1: batches 4-7
    const int row  = (blockIdx.x << 1) | (wv >> 1);   // 0..4095
    const size_t row4   = (size_t)row * (DD / 4);
    const size_t batch4 = (size_t)SS * (DD / 4);

    const f32x4* __restrict__ xp = reinterpret_cast<const f32x4*>(x);
    f32x4*       __restrict__ op = reinterpret_cast<f32x4*>(out);

    // ---- batch-0 row (both halves: stats input). NT: streamed once.
    f32x4 v[4];
#pragma unroll
    for (int c = 0; c < 4; ++c)
        v[c] = __builtin_nontemporal_load(xp + row4 + L + 64 * c);

    // ---- stats: 4 chains per lane; chain c covers k in [j0+1, j0+4], j0=256c+4L.
    // Seed mean_{j0} from the 6 preceding elements (closed-form factorial-decay
    // series); window pulled from neighbor lanes via shuffles.
    float var    = 0.0f;
    float m_last = 0.0f;
#pragma unroll
    for (int c = 0; c < 4; ++c) {
        const f32x4 up1 = shfl4_up1(v[c]);                 // lane L-1's chunk c
        const float u2z = __shfl_up(v[c].z, 2, 64);        // lane L-2 .z
        const float u2w = __shfl_up(v[c].w, 2, 64);        // lane L-2 .w
        f32x4 wrap1 = {0.f, 0.f, 0.f, 0.f};
        float wz = 0.f, ww = 0.f;
        if (c > 0) {                                       // compile-time (unrolled)
            wrap1 = shfl4(v[c - 1], 63);                   // elements 256c-4..256c-1
            wz = __shfl(v[c - 1].z, 62, 64);               // element 256c-6
            ww = __shfl(v[c - 1].w, 62, 64);               // element 256c-5
        }

        const float jf = (float)(256 * c + 4 * L);         // j0
        float m;
        if (c == 0 && L == 0) {
            m = 0.0f;                                      // mean_0, exact
        } else if (c == 0 && L == 1) {
            // exact: mean_4 = d4/4 + d3/12 + (d2+d1)/24
            m = up1.w * 0.25f + up1.z * (1.0f / 12.0f)
              + (up1.y + up1.x) * (1.0f / 24.0f);
        } else {
            // window w0..w5 = elements j0-6..j0-1
            const f32x4 w25 = (L == 0) ? wrap1 : up1;      // w2..w5
            float w0, w1;
            if (L >= 2)      { w0 = u2z;     w1 = u2w;     }
            else if (L == 1) { w0 = wrap1.z; w1 = wrap1.w; }
            else             { w0 = wz;      w1 = ww;      }
            float acc = w0;
            acc = fmaf(acc, __builtin_amdgcn_rcpf(jf - 5.0f), w1);
            acc = fmaf(acc, __builtin_amdgcn_rcpf(jf - 4.0f), w25.x);
            acc = fmaf(acc, __builtin_amdgcn_rcpf(jf - 3.0f), w25.y);
            acc = fmaf(acc, __builtin_amdgcn_rcpf(jf - 2.0f), w25.z);
            acc = fmaf(acc, __builtin_amdgcn_rcpf(jf - 1.0f), w25.w);
            m = acc * __builtin_amdgcn_rcpf(jf);
        }

        const float dd[4] = { v[c].x, v[c].y, v[c].z, v[c].w };
#pragma unroll
        for (int t = 0; t < 4; ++t) {
            m = (m + dd[t]) * __builtin_amdgcn_rcpf(jf + (float)(t + 1));
            const float df = dd[t] - m;
            var = fmaf(df, df, var);
        }
        m_last = m;                                        // c=3 end = mean_1024
    }

    // Butterfly: every lane gets the full var; broadcast mean_1024 from lane 63.
#pragma unroll
    for (int off = 32; off >= 1; off >>= 1) var += __shfl_xor(var, off, 64);
    const float mf = __shfl(m_last, 63, 64);
    const float r  = rsqrtf(var * (1.0f / 1023.0f) + EPSF);

    // ---- per-row scale/bias (alpha/beta consumed chunk-wise, never all live)
    const f32x4* __restrict__ a4 = reinterpret_cast<const f32x4*>(alpha);
    const f32x4* __restrict__ b4 = reinterpret_cast<const f32x4*>(beta);
    f32x4 sc[4], bs[4];
#pragma unroll
    for (int c = 0; c < 4; ++c) {
        const f32x4 av = a4[L + 64 * c];
        const f32x4 bv = b4[L + 64 * c];
        sc[c].x = av.x * r;  sc[c].y = av.y * r;
        sc[c].z = av.z * r;  sc[c].w = av.w * r;
        bs[c].x = fmaf(-mf, sc[c].x, bv.x);
        bs[c].y = fmaf(-mf, sc[c].y, bv.y);
        bs[c].z = fmaf(-mf, sc[c].z, bv.z);
        bs[c].w = fmaf(-mf, sc[c].w, bv.w);
    }

    if (half == 0) {
        // batch 0 straight from registers
#pragma unroll
        for (int c = 0; c < 4; ++c) {
            f32x4 o;
            o.x = fmaf(v[c].x, sc[c].x, bs[c].x);
            o.y = fmaf(v[c].y, sc[c].y, bs[c].y);
            o.z = fmaf(v[c].z, sc[c].z, bs[c].z);
            o.w = fmaf(v[c].w, sc[c].w, bs[c].w);
            __builtin_nontemporal_store(o, op + row4 + L + 64 * c);
        }
        // batches 1..3
#pragma unroll
        for (int b = 1; b <= 3; ++b) {
            const size_t base = row4 + (size_t)b * batch4;
            f32x4 cur[4];
#pragma unroll
            for (int c = 0; c < 4; ++c)
                cur[c] = __builtin_nontemporal_load(xp + base + L + 64 * c);
#pragma unroll
            for (int c = 0; c < 4; ++c) {
                f32x4 o;
                o.x = fmaf(cur[c].x, sc[c].x, bs[c].x);
                o.y = fmaf(cur[c].y, sc[c].y, bs[c].y);
                o.z = fmaf(cur[c].z, sc[c].z, bs[c].z);
                o.w = fmaf(cur[c].w, sc[c].w, bs[c].w);
                __builtin_nontemporal_store(o, op + base + L + 64 * c);
            }
        }
    } else {
        // batches 4..7
#pragma unroll
        for (int b = 4; b <= 7; ++b) {
            const size_t base = row4 + (size_t)b * batch4;
            f32x4 cur[4];
#pragma unroll
            for (int c = 0; c < 4; ++c)
                cur[c] = __builtin_nontemporal_load(xp + base + L + 64 * c);
#pragma unroll
            for (int c = 0; c < 4; ++c) {
                f32x4 o;
                o.x = fmaf(cur[c].x, sc[c].x, bs[c].x);
                o.y = fmaf(cur[c].y, sc[c].y, bs[c].y);
                o.z = fmaf(cur[c].z, sc[c].z, bs[c].z);
                o.w = fmaf(cur[c].w, sc[c].w, bs[c].w);
                __builtin_nontemporal_store(o, op + base + L + 64 * c);
            }
        }
    }
}

extern "C" void kernel_launch(void* const* d_in, const int* in_sizes, int n_in,
                              void* d_out, int out_size, void* d_ws, size_t ws_size,
                              hipStream_t stream) {
    (void)in_sizes; (void)n_in; (void)out_size; (void)d_ws; (void)ws_size;
    const float* x     = (const float*)d_in[0];   // (8, 4096, 1024) f32
    const float* alpha = (const float*)d_in[1];   // (1024,) f32
    const float* beta  = (const float*)d_in[2];   // (1024,) f32
    float* out = (float*)d_out;

    hipLaunchKernelGGL(fused_ln_kernel, dim3(SS / 2), dim3(256), 0, stream,
                       x, alpha, beta, out);
}

// Round 8
// 222.750 us; speedup vs baseline: 1.0644x; 1.0630x over previous
//
#include <hip/hip_runtime.h>
#include <math.h>

// LayerNorm_v2: B=8, S=4096, D=1024, f32 in / f32 out.
// Reference quirks replicated:
//  - stats from batch 0 only, broadcast over all batches
//  - "buggy Welford": mean_k=(mean_{k-1}+d_k)/k ; var += (d_k-mean_k)^2 ; var/=(D-1)
//
// v7b = v4 (measured best: single kernel, one wave per row, NT loads+stores,
// depth-2 batch pipeline, grid 1024x256) + the per-row scale/bias fold from
// v5 (out = x*sc + bs, 1 FMA/element). v5's cached-load change and v6's
// 2-waves/row change are both reverted (measured regressions: L2 thrash and
// lost ILP / NT-refetch respectively). This workload is per-wave-ILP-bound,
// not occupancy-bound: keep 8 VMEM ops in flight per wave.
// (Rounds 6/7 were container-level infra failures — resubmission, kernel
// renamed to defeat any stale build-cache replay.)
#define BB 8
#define SS 4096
#define DD 1024
#define EPSF 1e-5f

typedef float f32x4 __attribute__((ext_vector_type(4)));

__device__ __forceinline__ f32x4 shfl4(const f32x4 v, int lane) {
    f32x4 r;
    r.x = __shfl(v.x, lane, 64);
    r.y = __shfl(v.y, lane, 64);
    r.z = __shfl(v.z, lane, 64);
    r.w = __shfl(v.w, lane, 64);
    return r;
}
__device__ __forceinline__ f32x4 shfl4_up1(const f32x4 v) {
    f32x4 r;
    r.x = __shfl_up(v.x, 1, 64);
    r.y = __shfl_up(v.y, 1, 64);
    r.z = __shfl_up(v.z, 1, 64);
    r.w = __shfl_up(v.w, 1, 64);
    return r;
}

__global__ __launch_bounds__(256) void fused_ln_kernel_v7b(
    const float* __restrict__ x,
    const float* __restrict__ alpha,
    const float* __restrict__ beta,
    float* __restrict__ out)
{
    const int L   = threadIdx.x & 63;          // lane
    const int wv  = threadIdx.x >> 6;          // wave in block
    const int row = (blockIdx.x << 2) | wv;    // 0..4095, one row per wave
    const size_t row4   = (size_t)row * (DD / 4);
    const size_t batch4 = (size_t)SS * (DD / 4);

    const f32x4* __restrict__ xp = reinterpret_cast<const f32x4*>(x);
    f32x4*       __restrict__ op = reinterpret_cast<f32x4*>(out);

    // ---- batch-0 row, coalesced: lane L holds slots L+64c (floats 256c+4L..+3)
    f32x4 v[4];
#pragma unroll
    for (int c = 0; c < 4; ++c)
        v[c] = __builtin_nontemporal_load(xp + row4 + L + 64 * c);

    // ---- issue batch-1 + alpha/beta loads EARLY (independent of stats ALU)
    size_t cb = batch4 + row4;                 // current batch base (batch 1)
    f32x4 cur[4];
#pragma unroll
    for (int c = 0; c < 4; ++c)
        cur[c] = __builtin_nontemporal_load(xp + cb + L + 64 * c);

    const f32x4* __restrict__ a4 = reinterpret_cast<const f32x4*>(alpha);
    const f32x4* __restrict__ b4 = reinterpret_cast<const f32x4*>(beta);
    f32x4 av[4], bv[4];
#pragma unroll
    for (int c = 0; c < 4; ++c) { av[c] = a4[L + 64 * c]; bv[c] = b4[L + 64 * c]; }

    // ---- stats: 4 chains per lane; chain c covers k in [j0+1, j0+4], j0=256c+4L.
    // Seed mean_{j0} from the 6 preceding elements (closed-form factorial-decay
    // series); window pulled from neighbor lanes via shuffles.
    float var    = 0.0f;
    float m_last = 0.0f;
#pragma unroll
    for (int c = 0; c < 4; ++c) {
        const f32x4 up1 = shfl4_up1(v[c]);                 // lane L-1's chunk c
        const float u2z = __shfl_up(v[c].z, 2, 64);        // lane L-2 .z
        const float u2w = __shfl_up(v[c].w, 2, 64);        // lane L-2 .w
        f32x4 wrap1 = {0.f, 0.f, 0.f, 0.f};
        float wz = 0.f, ww = 0.f;
        if (c > 0) {                                       // compile-time (unrolled)
            wrap1 = shfl4(v[c - 1], 63);                   // elements 256c-4..256c-1
            wz = __shfl(v[c - 1].z, 62, 64);               // element 256c-6
            ww = __shfl(v[c - 1].w, 62, 64);               // element 256c-5
        }

        const float jf = (float)(256 * c + 4 * L);         // j0
        float m;
        if (c == 0 && L == 0) {
            m = 0.0f;                                      // mean_0, exact
        } else if (c == 0 && L == 1) {
            // exact: mean_4 = d4/4 + d3/12 + (d2+d1)/24
            m = up1.w * 0.25f + up1.z * (1.0f / 12.0f)
              + (up1.y + up1.x) * (1.0f / 24.0f);
        } else {
            // window w0..w5 = elements j0-6..j0-1
            const f32x4 w25 = (L == 0) ? wrap1 : up1;      // w2..w5
            float w0, w1;
            if (L >= 2)      { w0 = u2z;     w1 = u2w;     }
            else if (L == 1) { w0 = wrap1.z; w1 = wrap1.w; }
            else             { w0 = wz;      w1 = ww;      }
            float acc = w0;
            acc = fmaf(acc, __builtin_amdgcn_rcpf(jf - 5.0f), w1);
            acc = fmaf(acc, __builtin_amdgcn_rcpf(jf - 4.0f), w25.x);
            acc = fmaf(acc, __builtin_amdgcn_rcpf(jf - 3.0f), w25.y);
            acc = fmaf(acc, __builtin_amdgcn_rcpf(jf - 2.0f), w25.z);
            acc = fmaf(acc, __builtin_amdgcn_rcpf(jf - 1.0f), w25.w);
            m = acc * __builtin_amdgcn_rcpf(jf);
        }

        const float dd[4] = { v[c].x, v[c].y, v[c].z, v[c].w };
#pragma unroll
        for (int t = 0; t < 4; ++t) {
            m = (m + dd[t]) * __builtin_amdgcn_rcpf(jf + (float)(t + 1));
            const float df = dd[t] - m;
            var = fmaf(df, df, var);
        }
        m_last = m;                                        // c=3 end = mean_1024
    }

    // Butterfly: every lane gets the full var; broadcast mean_1024 from lane 63.
#pragma unroll
    for (int off = 32; off >= 1; off >>= 1) var += __shfl_xor(var, off, 64);
    const float mf = __shfl(m_last, 63, 64);
    const float r  = rsqrtf(var * (1.0f / 1023.0f) + EPSF);

    // ---- per-row scale/bias: out = x*sc + bs  (1 FMA per element streaming)
    f32x4 sc[4], bs[4];
#pragma unroll
    for (int c = 0; c < 4; ++c) {
        sc[c].x = av[c].x * r;  sc[c].y = av[c].y * r;
        sc[c].z = av[c].z * r;  sc[c].w = av[c].w * r;
        bs[c].x = fmaf(-mf, sc[c].x, bv[c].x);
        bs[c].y = fmaf(-mf, sc[c].y, bv[c].y);
        bs[c].z = fmaf(-mf, sc[c].z, bv[c].z);
        bs[c].w = fmaf(-mf, sc[c].w, bv[c].w);
    }

    // ---- normalize batch 0 straight from registers (coalesced NT stores)
#pragma unroll
    for (int c = 0; c < 4; ++c) {
        f32x4 o;
        o.x = fmaf(v[c].x, sc[c].x, bs[c].x);
        o.y = fmaf(v[c].y, sc[c].y, bs[c].y);
        o.z = fmaf(v[c].z, sc[c].z, bs[c].z);
        o.w = fmaf(v[c].w, sc[c].w, bs[c].w);
        __builtin_nontemporal_store(o, op + row4 + L + 64 * c);
    }

    // ---- stream batches 1..7, depth-2 pipeline (load b+1 before storing b)
#pragma unroll
    for (int b = 1; b <= 6; ++b) {
        f32x4 nxt[4];
#pragma unroll
        for (int c = 0; c < 4; ++c)
            nxt[c] = __builtin_nontemporal_load(xp + cb + batch4 + L + 64 * c);
#pragma unroll
        for (int c = 0; c < 4; ++c) {
            f32x4 o;
            o.x = fmaf(cur[c].x, sc[c].x, bs[c].x);
            o.y = fmaf(cur[c].y, sc[c].y, bs[c].y);
            o.z = fmaf(cur[c].z, sc[c].z, bs[c].z);
            o.w = fmaf(cur[c].w, sc[c].w, bs[c].w);
            __builtin_nontemporal_store(o, op + cb + L + 64 * c);
        }
#pragma unroll
        for (int c = 0; c < 4; ++c) cur[c] = nxt[c];
        cb += batch4;
    }
    // epilogue: batch 7
#pragma unroll
    for (int c = 0; c < 4; ++c) {
        f32x4 o;
        o.x = fmaf(cur[c].x, sc[c].x, bs[c].x);
        o.y = fmaf(cur[c].y, sc[c].y, bs[c].y);
        o.z = fmaf(cur[c].z, sc[c].z, bs[c].z);
        o.w = fmaf(cur[c].w, sc[c].w, bs[c].w);
        __builtin_nontemporal_store(o, op + cb + L + 64 * c);
    }
}

extern "C" void kernel_launch(void* const* d_in, const int* in_sizes, int n_in,
                              void* d_out, int out_size, void* d_ws, size_t ws_size,
                              hipStream_t stream) {
    (void)in_sizes; (void)n_in; (void)out_size; (void)d_ws; (void)ws_size;
    const float* x     = (const float*)d_in[0];   // (8, 4096, 1024) f32
    const float* alpha = (const float*)d_in[1];   // (1024,) f32
    const float* beta  = (const float*)d_in[2];   // (1024,) f32
    float* out = (float*)d_out;

    hipLaunchKernelGGL(fused_ln_kernel_v7b, dim3(SS / 4), dim3(256), 0, stream,
                       x, alpha, beta, out);
}